// Round 1
// baseline (710.699 us; speedup 1.0000x reference)
//
#include <hip/hip_runtime.h>
#include <math.h>

// Problem constants (from reference): B=16, DIM=512, SIZE=128
#define BB   16
#define CC   512
#define SS   128
#define HWSZ (SS * SS)   // 16384

// -----------------------------------------------------------------------------
// Kernel 1: channel reduction  x2[b,o,h,w] = sum_c x[b,c,h,w] * wconv[o,c]
// One block per (b,h) row. 256 threads: lane covers 4 consecutive w (float4),
// 8 c-groups strided over the 512 channels; LDS reduce over groups.
// Writes x2 in BOTH [b,2,h,w] and transposed [b,2,w,h] layouts so kernel 2
// gets fully coalesced reads for both the w-direction and h-direction convs.
// -----------------------------------------------------------------------------
__global__ __launch_bounds__(256) void k1_channel_reduce(
    const float* __restrict__ x, const float* __restrict__ wconv,
    float* __restrict__ x2, float* __restrict__ x2t)
{
    __shared__ float wsA[CC];
    __shared__ float wsB[CC];
    __shared__ float red[2][8][SS];

    const int tid = threadIdx.x;
    for (int i = tid; i < CC; i += 256) {
        wsA[i] = wconv[i];        // o = 0
        wsB[i] = wconv[CC + i];   // o = 1
    }
    __syncthreads();

    const int bh = blockIdx.x;       // 0..2047
    const int b  = bh >> 7;
    const int h  = bh & 127;
    const int wl = tid & 31;         // w quad index (4 floats each)
    const int cg = tid >> 5;         // 0..7 channel group
    const size_t base = (size_t)b * CC * HWSZ + (size_t)h * SS + (size_t)(wl * 4);

    float4 a0 = make_float4(0.f, 0.f, 0.f, 0.f);
    float4 a1 = make_float4(0.f, 0.f, 0.f, 0.f);
    #pragma unroll 4
    for (int c = cg; c < CC; c += 8) {
        const float4 xv = *(const float4*)(x + base + (size_t)c * HWSZ);
        const float wa = wsA[c];
        const float wb = wsB[c];
        a0.x = fmaf(xv.x, wa, a0.x); a0.y = fmaf(xv.y, wa, a0.y);
        a0.z = fmaf(xv.z, wa, a0.z); a0.w = fmaf(xv.w, wa, a0.w);
        a1.x = fmaf(xv.x, wb, a1.x); a1.y = fmaf(xv.y, wb, a1.y);
        a1.z = fmaf(xv.z, wb, a1.z); a1.w = fmaf(xv.w, wb, a1.w);
    }
    *(float4*)&red[0][cg][wl * 4] = a0;
    *(float4*)&red[1][cg][wl * 4] = a1;
    __syncthreads();

    const int o = tid >> 7;      // output channel 0/1
    const int w = tid & 127;     // w position
    float s = 0.f;
    #pragma unroll
    for (int g = 0; g < 8; ++g) s += red[o][g][w];
    x2 [((size_t)(b * 2 + o) * SS + h) * SS + w] = s;
    x2t[((size_t)(b * 2 + o) * SS + w) * SS + h] = s;
}

// -----------------------------------------------------------------------------
// Kernel 2: everything else, one block per batch element b (16 blocks, 256 thr).
//
// ww conv:  ww[wo] = sum_{i,kh,kw} x2[b,i,kh,wo+kw-2] * Www[i,kh,kw]
//   factored: tw[kw][w'] = sum_{i,kh} x2[i,kh,w'] * Www[i,kh,kw]   (x read once)
//             ww[wo]     = sum_kw tw[kw][wo+kw-2]  (zero-pad outside [0,128))
// hw conv:  symmetric via x2t.
// Then linear+sigmoid per branch, then the [128]x[128] outer product store.
// -----------------------------------------------------------------------------
__global__ __launch_bounds__(256) void k2_rest(
    const float* __restrict__ x2, const float* __restrict__ x2t,
    const float* __restrict__ wwc,   // [2,128,5]
    const float* __restrict__ hwc,   // [2,5,128]
    const float* __restrict__ wlw, const float* __restrict__ wlb,
    const float* __restrict__ hlw, const float* __restrict__ hlb,
    float* __restrict__ out)
{
    __shared__ float tw[2][5][SS];   // ww partials, per input channel half
    __shared__ float uh[2][5][SS];   // hw partials
    __shared__ float vbuf[2 * SS];   // conv outputs: [0..127]=ww, [128..255]=hw
    __shared__ float rbuf[2 * SS];   // post-sigmoid: [0..127]=ww2, [128..255]=hw2

    const int b        = blockIdx.x;
    const int tid      = threadIdx.x;
    const int lane_pos = tid & 127;   // wo or ho
    const int half     = tid >> 7;    // input channel i of x2 (wave-uniform)
    const int half_u   = __builtin_amdgcn_readfirstlane(half); // force SGPR -> s_load weights

    // phase 1: tw[half][kw][wo] = sum_kh x2[b,half,kh,wo] * wwc[half,kh,kw]
    {
        const float* xrow = x2 + (size_t)(b * 2 + half) * HWSZ + lane_pos;
        const float* wrow = wwc + half_u * (SS * 5);
        float acc[5] = {0.f, 0.f, 0.f, 0.f, 0.f};
        for (int kh = 0; kh < SS; ++kh) {
            const float xv = xrow[(size_t)kh * SS];   // coalesced across lanes
            #pragma unroll
            for (int kw = 0; kw < 5; ++kw)
                acc[kw] = fmaf(xv, wrow[kh * 5 + kw], acc[kw]);
        }
        #pragma unroll
        for (int kw = 0; kw < 5; ++kw) tw[half][kw][lane_pos] = acc[kw];
    }

    // phase 2: uh[half][kh][ho] = sum_kw x2t[b,half,kw,ho] * hwc[half,kh,kw]
    {
        const float* xcol = x2t + (size_t)(b * 2 + half) * HWSZ + lane_pos;
        const float* wrow = hwc + half_u * (5 * SS);
        float acc[5] = {0.f, 0.f, 0.f, 0.f, 0.f};
        for (int kw = 0; kw < SS; ++kw) {
            const float xv = xcol[(size_t)kw * SS];   // coalesced (transposed layout)
            #pragma unroll
            for (int kh = 0; kh < 5; ++kh)
                acc[kh] = fmaf(xv, wrow[kh * SS + kw], acc[kh]);
        }
        #pragma unroll
        for (int kh = 0; kh < 5; ++kh) uh[half][kh][lane_pos] = acc[kh];
    }
    __syncthreads();

    // phase 3: shifted combine -> conv outputs
    {
        float s = 0.f;
        if (half == 0) {
            const int wo = lane_pos;
            #pragma unroll
            for (int kw = 0; kw < 5; ++kw) {
                const int wsrc = wo + kw - 2;
                if (wsrc >= 0 && wsrc < SS) s += tw[0][kw][wsrc] + tw[1][kw][wsrc];
            }
        } else {
            const int ho = lane_pos;
            #pragma unroll
            for (int kh = 0; kh < 5; ++kh) {
                const int hsrc = ho + kh - 2;
                if (hsrc >= 0 && hsrc < SS) s += uh[0][kh][hsrc] + uh[1][kh][hsrc];
            }
        }
        vbuf[tid] = s;
    }
    __syncthreads();

    // phase 4: linear (out[j] = sum_k v[k] * W[j,k] + b[j]) + sigmoid
    {
        const int j = lane_pos;
        const float* lw  = (half == 0) ? wlw : hlw;
        const float* lb  = (half == 0) ? wlb : hlb;
        const float* vin = vbuf + half * SS;   // LDS broadcast reads
        float s = lb[j];
        const float4* wr = (const float4*)(lw + (size_t)j * SS);  // own contiguous row
        #pragma unroll 4
        for (int k4 = 0; k4 < SS / 4; ++k4) {
            const float4 wv = wr[k4];
            s = fmaf(vin[4 * k4 + 0], wv.x, s);
            s = fmaf(vin[4 * k4 + 1], wv.y, s);
            s = fmaf(vin[4 * k4 + 2], wv.z, s);
            s = fmaf(vin[4 * k4 + 3], wv.w, s);
        }
        rbuf[tid] = 1.f / (1.f + expf(-s));
    }
    __syncthreads();

    // phase 5: out[b,h,w] = hw2[h] * ww2[w]  (float4 coalesced stores)
    {
        float* ob = out + (size_t)b * HWSZ;
        for (int p4 = tid; p4 < HWSZ / 4; p4 += 256) {
            const int h  = p4 >> 5;
            const int w0 = (p4 & 31) * 4;
            const float hv = rbuf[SS + h];
            float4 o;
            o.x = hv * rbuf[w0 + 0];
            o.y = hv * rbuf[w0 + 1];
            o.z = hv * rbuf[w0 + 2];
            o.w = hv * rbuf[w0 + 3];
            *(float4*)(ob + (size_t)h * SS + w0) = o;
        }
    }
}

extern "C" void kernel_launch(void* const* d_in, const int* in_sizes, int n_in,
                              void* d_out, int out_size, void* d_ws, size_t ws_size,
                              hipStream_t stream) {
    const float* x     = (const float*)d_in[0];  // [16,512,128,128]
    const float* wconv = (const float*)d_in[1];  // [2,512,1,1]
    const float* wwc   = (const float*)d_in[2];  // [1,2,128,5]
    const float* hwc   = (const float*)d_in[3];  // [1,2,5,128]
    const float* wlw   = (const float*)d_in[4];  // [128,128]
    const float* wlb   = (const float*)d_in[5];  // [128]
    const float* hlw   = (const float*)d_in[6];  // [128,128]
    const float* hlb   = (const float*)d_in[7];  // [128]
    float* out = (float*)d_out;                  // [16,128,128] fp32

    // workspace: x2 (2 MB) + x2t (2 MB), both fp32
    float* x2  = (float*)d_ws;
    float* x2t = x2 + (size_t)BB * 2 * HWSZ;

    k1_channel_reduce<<<dim3(BB * SS), dim3(256), 0, stream>>>(x, wconv, x2, x2t);
    k2_rest<<<dim3(BB), dim3(256), 0, stream>>>(x2, x2t, wwc, hwc,
                                                wlw, wlb, hlw, hlb, out);
}

// Round 2
// 693.160 us; speedup vs baseline: 1.0253x; 1.0253x over previous
//
#include <hip/hip_runtime.h>
#include <math.h>

// Problem constants (from reference): B=16, DIM=512, SIZE=128
#define BB   16
#define CC   512
#define SS   128
#define HWSZ (SS * SS)   // 16384

// -----------------------------------------------------------------------------
// Kernel 1: channel reduction  x2[b,o,h,w] = sum_c x[b,c,h,w] * wconv[o,c]
//
// Re-tiled for DRAM page locality: one block per (b, 4-row tile).
// grid = 16*32 = 512 blocks, 128 threads. Each thread owns ONE float4 output
// position (4 rows x 128 w = 512 floats = 128 quads) and loops over all 512
// channels sequentially. Per channel the block reads 2 KB CONTIGUOUS (vs the
// old 512-B chunks), and the 32 same-b blocks sweep each 64-KB channel plane
// together front-to-back. No cross-thread reduction; accumulators in regs.
// Writes x2 in both [b,2,h,w] and transposed [b,2,w,h] layouts for kernel 2.
// -----------------------------------------------------------------------------
__global__ __launch_bounds__(128) void k1_channel_reduce(
    const float* __restrict__ x, const float* __restrict__ wconv,
    float* __restrict__ x2, float* __restrict__ x2t)
{
    __shared__ float wsA[CC];
    __shared__ float wsB[CC];

    const int tid = threadIdx.x;
    for (int i = tid; i < CC; i += 128) {
        wsA[i] = wconv[i];        // o = 0
        wsB[i] = wconv[CC + i];   // o = 1
    }
    __syncthreads();

    const int b  = blockIdx.x >> 5;   // 32 tiles per batch
    const int tg = blockIdx.x & 31;   // tile = rows tg*4 .. tg*4+3
    // This thread's quad within the 4x128 tile (flat float index tid*4).
    const float* xp = x + (size_t)b * CC * HWSZ + (size_t)tg * (4 * SS) + tid * 4;

    float4 a0 = make_float4(0.f, 0.f, 0.f, 0.f);   // o = 0
    float4 a1 = make_float4(0.f, 0.f, 0.f, 0.f);   // o = 1
    #pragma unroll 8
    for (int c = 0; c < CC; ++c) {
        const float4 v = *(const float4*)(xp + (size_t)c * HWSZ);
        const float wa = wsA[c];
        const float wb = wsB[c];
        a0.x = fmaf(v.x, wa, a0.x); a0.y = fmaf(v.y, wa, a0.y);
        a0.z = fmaf(v.z, wa, a0.z); a0.w = fmaf(v.w, wa, a0.w);
        a1.x = fmaf(v.x, wb, a1.x); a1.y = fmaf(v.y, wb, a1.y);
        a1.z = fmaf(v.z, wb, a1.z); a1.w = fmaf(v.w, wb, a1.w);
    }

    const int hloc = tid >> 5;          // 0..3 row within tile
    const int w0   = (tid & 31) * 4;    // w of this quad
    const int h    = tg * 4 + hloc;

    *(float4*)&x2[((size_t)(b * 2 + 0) * SS + h) * SS + w0] = a0;
    *(float4*)&x2[((size_t)(b * 2 + 1) * SS + h) * SS + w0] = a1;

    // transposed layout: scattered dwords, 2 MB total -> L2 absorbs
    x2t[((size_t)(b * 2 + 0) * SS + (w0 + 0)) * SS + h] = a0.x;
    x2t[((size_t)(b * 2 + 0) * SS + (w0 + 1)) * SS + h] = a0.y;
    x2t[((size_t)(b * 2 + 0) * SS + (w0 + 2)) * SS + h] = a0.z;
    x2t[((size_t)(b * 2 + 0) * SS + (w0 + 3)) * SS + h] = a0.w;
    x2t[((size_t)(b * 2 + 1) * SS + (w0 + 0)) * SS + h] = a1.x;
    x2t[((size_t)(b * 2 + 1) * SS + (w0 + 1)) * SS + h] = a1.y;
    x2t[((size_t)(b * 2 + 1) * SS + (w0 + 2)) * SS + h] = a1.z;
    x2t[((size_t)(b * 2 + 1) * SS + (w0 + 3)) * SS + h] = a1.w;
}

// -----------------------------------------------------------------------------
// Kernel 2: everything else, one block per batch element b (16 blocks, 256 thr).
//
// ww conv:  ww[wo] = sum_{i,kh,kw} x2[b,i,kh,wo+kw-2] * Www[i,kh,kw]
//   factored: tw[kw][w'] = sum_{i,kh} x2[i,kh,w'] * Www[i,kh,kw]   (x read once)
//             ww[wo]     = sum_kw tw[kw][wo+kw-2]  (zero-pad outside [0,128))
// hw conv:  symmetric via x2t.
// Then linear+sigmoid per branch, then the [128]x[128] outer product store.
// -----------------------------------------------------------------------------
__global__ __launch_bounds__(256) void k2_rest(
    const float* __restrict__ x2, const float* __restrict__ x2t,
    const float* __restrict__ wwc,   // [2,128,5]
    const float* __restrict__ hwc,   // [2,5,128]
    const float* __restrict__ wlw, const float* __restrict__ wlb,
    const float* __restrict__ hlw, const float* __restrict__ hlb,
    float* __restrict__ out)
{
    __shared__ float tw[2][5][SS];   // ww partials, per input channel half
    __shared__ float uh[2][5][SS];   // hw partials
    __shared__ float vbuf[2 * SS];   // conv outputs: [0..127]=ww, [128..255]=hw
    __shared__ float rbuf[2 * SS];   // post-sigmoid: [0..127]=ww2, [128..255]=hw2

    const int b        = blockIdx.x;
    const int tid      = threadIdx.x;
    const int lane_pos = tid & 127;   // wo or ho
    const int half     = tid >> 7;    // input channel i of x2 (wave-uniform)
    const int half_u   = __builtin_amdgcn_readfirstlane(half); // force SGPR -> s_load weights

    // phase 1: tw[half][kw][wo] = sum_kh x2[b,half,kh,wo] * wwc[half,kh,kw]
    {
        const float* xrow = x2 + (size_t)(b * 2 + half) * HWSZ + lane_pos;
        const float* wrow = wwc + half_u * (SS * 5);
        float acc[5] = {0.f, 0.f, 0.f, 0.f, 0.f};
        #pragma unroll 8
        for (int kh = 0; kh < SS; ++kh) {
            const float xv = xrow[(size_t)kh * SS];   // coalesced across lanes
            #pragma unroll
            for (int kw = 0; kw < 5; ++kw)
                acc[kw] = fmaf(xv, wrow[kh * 5 + kw], acc[kw]);
        }
        #pragma unroll
        for (int kw = 0; kw < 5; ++kw) tw[half][kw][lane_pos] = acc[kw];
    }

    // phase 2: uh[half][kh][ho] = sum_kw x2t[b,half,kw,ho] * hwc[half,kh,kw]
    {
        const float* xcol = x2t + (size_t)(b * 2 + half) * HWSZ + lane_pos;
        const float* wrow = hwc + half_u * (5 * SS);
        float acc[5] = {0.f, 0.f, 0.f, 0.f, 0.f};
        #pragma unroll 8
        for (int kw = 0; kw < SS; ++kw) {
            const float xv = xcol[(size_t)kw * SS];   // coalesced (transposed layout)
            #pragma unroll
            for (int kh = 0; kh < 5; ++kh)
                acc[kh] = fmaf(xv, wrow[kh * SS + kw], acc[kh]);
        }
        #pragma unroll
        for (int kh = 0; kh < 5; ++kh) uh[half][kh][lane_pos] = acc[kh];
    }
    __syncthreads();

    // phase 3: shifted combine -> conv outputs
    {
        float s = 0.f;
        if (half == 0) {
            const int wo = lane_pos;
            #pragma unroll
            for (int kw = 0; kw < 5; ++kw) {
                const int wsrc = wo + kw - 2;
                if (wsrc >= 0 && wsrc < SS) s += tw[0][kw][wsrc] + tw[1][kw][wsrc];
            }
        } else {
            const int ho = lane_pos;
            #pragma unroll
            for (int kh = 0; kh < 5; ++kh) {
                const int hsrc = ho + kh - 2;
                if (hsrc >= 0 && hsrc < SS) s += uh[0][kh][hsrc] + uh[1][kh][hsrc];
            }
        }
        vbuf[tid] = s;
    }
    __syncthreads();

    // phase 4: linear (out[j] = sum_k v[k] * W[j,k] + b[j]) + sigmoid
    {
        const int j = lane_pos;
        const float* lw  = (half == 0) ? wlw : hlw;
        const float* lb  = (half == 0) ? wlb : hlb;
        const float* vin = vbuf + half * SS;   // LDS broadcast reads
        float s = lb[j];
        const float4* wr = (const float4*)(lw + (size_t)j * SS);  // own contiguous row
        #pragma unroll 4
        for (int k4 = 0; k4 < SS / 4; ++k4) {
            const float4 wv = wr[k4];
            s = fmaf(vin[4 * k4 + 0], wv.x, s);
            s = fmaf(vin[4 * k4 + 1], wv.y, s);
            s = fmaf(vin[4 * k4 + 2], wv.z, s);
            s = fmaf(vin[4 * k4 + 3], wv.w, s);
        }
        rbuf[tid] = 1.f / (1.f + expf(-s));
    }
    __syncthreads();

    // phase 5: out[b,h,w] = hw2[h] * ww2[w]  (float4 coalesced stores)
    {
        float* ob = out + (size_t)b * HWSZ;
        for (int p4 = tid; p4 < HWSZ / 4; p4 += 256) {
            const int h  = p4 >> 5;
            const int w0 = (p4 & 31) * 4;
            const float hv = rbuf[SS + h];
            float4 o;
            o.x = hv * rbuf[w0 + 0];
            o.y = hv * rbuf[w0 + 1];
            o.z = hv * rbuf[w0 + 2];
            o.w = hv * rbuf[w0 + 3];
            *(float4*)(ob + (size_t)h * SS + w0) = o;
        }
    }
}

extern "C" void kernel_launch(void* const* d_in, const int* in_sizes, int n_in,
                              void* d_out, int out_size, void* d_ws, size_t ws_size,
                              hipStream_t stream) {
    const float* x     = (const float*)d_in[0];  // [16,512,128,128]
    const float* wconv = (const float*)d_in[1];  // [2,512,1,1]
    const float* wwc   = (const float*)d_in[2];  // [1,2,128,5]
    const float* hwc   = (const float*)d_in[3];  // [1,2,5,128]
    const float* wlw   = (const float*)d_in[4];  // [128,128]
    const float* wlb   = (const float*)d_in[5];  // [128]
    const float* hlw   = (const float*)d_in[6];  // [128,128]
    const float* hlb   = (const float*)d_in[7];  // [128]
    float* out = (float*)d_out;                  // [16,128,128] fp32

    // workspace: x2 (2 MB) + x2t (2 MB), both fp32
    float* x2  = (float*)d_ws;
    float* x2t = x2 + (size_t)BB * 2 * HWSZ;

    k1_channel_reduce<<<dim3(BB * 32), dim3(128), 0, stream>>>(x, wconv, x2, x2t);
    k2_rest<<<dim3(BB), dim3(256), 0, stream>>>(x2, x2t, wwc, hwc,
                                                wlw, wlb, hlw, hlb, out);
}